// Round 19
// baseline (42.834 us; speedup 1.0000x reference)
//
#include <hip/hip_runtime.h>
#include <hip/hip_bf16.h>

typedef unsigned short u16;
typedef unsigned char u8;
typedef unsigned int u32;
typedef __attribute__((ext_vector_type(4))) unsigned int u32x4;
typedef __attribute__((ext_vector_type(8))) int i32x8;
typedef __attribute__((ext_vector_type(16))) float f32x16;

#define L_SEQ 4096
#define NCH 64
#define NBATCH 4
#define NW 8                    // waves per block = KV splits
#define KVSPAN (L_SEQ / NW)     // 512 j per wave (8 tiles of 64)
#define TPS (KVSPAN / 64)
#define QB 32                   // q-rows per block (shared by all waves)
#define LOG2E 1.4426950408889634f
#define C2 (3.0f * LOG2E)       // constant softmax shift; cancels in O/l
#define SCL1 127                // e8m0 encoding of 1.0

// packed f32 pair -> 2x fp8 e4m3 into low (WORD=false) or high (WORD=true) 16 bits.
template <bool WORD>
__device__ inline u32 pk_fp8(float a, float b, u32 old) {
    return (u32)__builtin_amdgcn_cvt_pk_fp8_f32(a, b, (int)old, WORD);
}
__device__ inline u8 fp8_1(float a) {
    return (u8)(__builtin_amdgcn_cvt_pk_fp8_f32(a, a, 0, false) & 0xff);
}

union I8 { u32x4 q[2]; i32x8 v; };
union PU { u32 u[8]; i32x8 v; };

// ---------------- Kernel 1: QKV projection -> fp8 fragment-order workspace --------
// (R17-proven: 32-px blocks, 512 blocks = 2 blocks/CU.)
// Qp8[n][i][c] row-major, Q pre-scaled by log2e.
// Kp8 addr(j,c) = (j>>5)*2048 + ((c>>4)&1)*1024 + ((j&31)+((c>>5)<<5))*16 + (c&15).
// Vp8 addr(c,j) = (j>>6)*4096 + (c>>5)*2048 + ((j>>5)&1)*1024
//               + ((c&31)+(h<<5))*16 + el,  h=((j&31)>>2)&1, el=(j&3)+4*((j&31)>>3).
__global__ __launch_bounds__(256) void qkv_kernel(
    const float* __restrict__ x,
    const float* __restrict__ wb, const float* __restrict__ bb,
    const float* __restrict__ wc, const float* __restrict__ bc,
    const float* __restrict__ wd, const float* __restrict__ bd,
    u8* __restrict__ Qp8, u8* __restrict__ Kp8, u8* __restrict__ Vp8)
{
    __shared__ float xs[64][32];       // x tile: [c][px], 8 KB
    __shared__ float wl[3][64][65];    // padded weights: [mat][o][c], 49.9 KB

    const int nb  = blockIdx.y;
    const int i0  = blockIdx.x * 32;
    const int tid = threadIdx.x;

    const float* xbase = x + (size_t)nb * NCH * L_SEQ + i0;
    #pragma unroll
    for (int rep = 0; rep < 8; ++rep) {
        int idx = rep * 256 + tid;
        int c = idx >> 5, px = idx & 31;
        xs[c][px] = xbase[(size_t)c * L_SEQ + px];
    }
    const float* wsrc[3] = { wb, wc, wd };
    for (int m = 0; m < 3; ++m) {
        #pragma unroll
        for (int rep = 0; rep < 16; ++rep) {
            int idx = rep * 256 + tid;
            wl[m][idx >> 6][idx & 63] = wsrc[m][idx];
        }
    }
    __syncthreads();

    const int co  = tid & 63;     // output channel
    const int pg  = tid >> 6;     // pixel group 0..3 (8 px each)
    const int px0 = pg * 8;

    float accB[8], accC[8], accD[8];
    const float biasB = bb[co], biasC = bc[co], biasD = bd[co];
    #pragma unroll
    for (int p = 0; p < 8; ++p) { accB[p] = biasB; accC[p] = biasC; accD[p] = biasD; }

    for (int c = 0; c < 64; ++c) {
        const float wbv = wl[0][co][c];
        const float wcv = wl[1][co][c];
        const float wdv = wl[2][co][c];
        #pragma unroll
        for (int p = 0; p < 8; ++p) {
            const float xv = xs[c][px0 + p];
            accB[p] += wbv * xv;
            accC[p] += wcv * xv;
            accD[p] += wdv * xv;
        }
    }

    const size_t nbase = (size_t)nb * L_SEQ * NCH;   // bytes per batch = 262144

    const int kbase = (i0 >> 5) * 2048 + ((co >> 4) & 1) * 1024 + (co >> 5) * 512
                    + pg * 128 + (co & 15);
    const int vbase = (i0 >> 6) * 4096 + (co >> 5) * 2048 + ((i0 >> 5) & 1) * 1024
                    + (co & 31) * 16 + 4 * pg;

    #pragma unroll
    for (int p = 0; p < 8; ++p) {
        const int i = i0 + px0 + p;
        Kp8[nbase + kbase + p * 16]      = fp8_1(accB[p]);                   // keys = xb
        Qp8[nbase + (size_t)i * 64 + co] = fp8_1(accC[p] * LOG2E);           // queries (log2e-folded)
    }
    {                                                                         // values = xd
        u32 w0 = pk_fp8<false>(accD[0], accD[1], 0);
        w0     = pk_fp8<true >(accD[2], accD[3], w0);
        u32 w1 = pk_fp8<false>(accD[4], accD[5], 0);
        w1     = pk_fp8<true >(accD[6], accD[7], w1);
        *(u32*)&Vp8[nbase + vbase]       = w0;
        *(u32*)&Vp8[nbase + vbase + 512] = w1;
    }
}

// ---------------- Kernel 2: flash attention, MX-scaled 32x32x64 fp8 ---------------
// R16 math, ONE change: launch_bounds (512,4) -> (512,2). Honest live-register
// count is ~135 (acc 32 + kf/vf 32 + s 32 + qf 8 + pb 8 + addr/sys) > the 128
// budget (512,4) imposes -> suspected silent spill (invisible: fills own the
// rocprof top-5). 256-VGPR budget guarantees no spill; occupancy 4->2 waves/SIMD
// is ~neutral per R8/R15 (wave count null in 2048-8192 range).
__global__ __launch_bounds__(512, 2) void attn_kernel(
    const u8* __restrict__ Qp8, const u8* __restrict__ Kp8,
    const u8* __restrict__ Vp8, const float* __restrict__ x,
    const float* __restrict__ alphap, float* __restrict__ out)
{
    __shared__ float smem[NW][QB * 65];   // per-wave partial O [q][c], pad 65
    __shared__ float lbuf[NW][QB];        // per-wave partial l

    const int nb   = blockIdx.y;
    const int i0   = blockIdx.x * QB;
    const int tid  = threadIdx.x;
    const int w    = tid >> 6;
    const int lane = tid & 63;
    const int i_l  = lane & 31;    // q-row owned by this lane
    const int h2   = lane >> 5;    // k-half

    // Q fragment (B operand): B[k=c=h2*32+e][col=i], 32 consecutive bytes
    I8 qf;
    {
        const u8* qrow = Qp8 + (size_t)(nb * L_SEQ + i0 + i_l) * 64 + h2 * 32;
        qf.q[0] = *(const u32x4*)(qrow);
        qf.q[1] = *(const u32x4*)(qrow + 16);
    }

    f32x16 acc[2] = {};   // [ct]: O^T[c = ct*32 + (r&3)+8*(r>>2)+4*h2][i = i_l]
    float l_ = 0.f;

    const u8* KpB = Kp8 + (size_t)nb * L_SEQ * NCH;
    const u8* VpB = Vp8 + (size_t)nb * NCH * L_SEQ;

    #pragma unroll 1
    for (int t = 0; t < TPS; ++t) {
        const int j0 = w * KVSPAN + t * 64;

        // ---- coalesced fragment loads: 8x dwordx4 per tile ----
        I8 kf0, kf1, vf0, vf1;
        {
            const u8* kb = KpB + (size_t)(j0 >> 5) * 2048 + lane * 16;
            kf0.q[0] = *(const u32x4*)(kb);
            kf0.q[1] = *(const u32x4*)(kb + 1024);
            kf1.q[0] = *(const u32x4*)(kb + 2048);
            kf1.q[1] = *(const u32x4*)(kb + 3072);
            const u8* vb = VpB + (size_t)(j0 >> 6) * 4096 + lane * 16;
            vf0.q[0] = *(const u32x4*)(vb);
            vf0.q[1] = *(const u32x4*)(vb + 1024);
            vf1.q[0] = *(const u32x4*)(vb + 2048);
            vf1.q[1] = *(const u32x4*)(vb + 3072);
        }

        // ---- S^T = K Q^T (two 32j x 32i MFMA over K=64) ----
        f32x16 z = {};
        f32x16 s0 = __builtin_amdgcn_mfma_scale_f32_32x32x64_f8f6f4(
            kf0.v, qf.v, z, 0, 0, 0, SCL1, 0, SCL1);
        f32x16 s1 = __builtin_amdgcn_mfma_scale_f32_32x32x64_f8f6f4(
            kf1.v, qf.v, z, 0, 0, 0, SCL1, 0, SCL1);

        // ---- constant-shift softmax: P' = 2^(S2 - C2) ----
        #pragma unroll
        for (int r = 0; r < 16; ++r) {
            s0[r] = exp2f(s0[r] - C2);
            s1[r] = exp2f(s1[r] - C2);
        }
        {
            const float a0 = (s0[0] + s0[1]) + (s0[2] + s0[3]);
            const float a1 = (s0[4] + s0[5]) + (s0[6] + s0[7]);
            const float a2 = (s0[8] + s0[9]) + (s0[10] + s0[11]);
            const float a3 = (s0[12] + s0[13]) + (s0[14] + s0[15]);
            const float b0 = (s1[0] + s1[1]) + (s1[2] + s1[3]);
            const float b1 = (s1[4] + s1[5]) + (s1[6] + s1[7]);
            const float b2 = (s1[8] + s1[9]) + (s1[10] + s1[11]);
            const float b3 = (s1[12] + s1[13]) + (s1[14] + s1[15]);
            float rs = ((a0 + a1) + (a2 + a3)) + ((b0 + b1) + (b2 + b3));
            rs += __shfl_xor(rs, 32, 64);   // lanes i and i+32 share row i
            l_ += rs;
        }

        // ---- pack P' to fp8 B-fragment: slot e<16 -> s0[e], e>=16 -> s1[e-16] ----
        PU pb;
        #pragma unroll
        for (int r = 0; r < 4; ++r)
            pb.u[r] = pk_fp8<true>(s0[4 * r + 2], s0[4 * r + 3],
                      pk_fp8<false>(s0[4 * r], s0[4 * r + 1], 0));
        #pragma unroll
        for (int r = 0; r < 4; ++r)
            pb.u[4 + r] = pk_fp8<true>(s1[4 * r + 2], s1[4 * r + 3],
                          pk_fp8<false>(s1[4 * r], s1[4 * r + 1], 0));

        // ---- O^T += V^T P'^T (two 32c x 32i MFMA over K=64 j-slots) ----
        acc[0] = __builtin_amdgcn_mfma_scale_f32_32x32x64_f8f6f4(
            vf0.v, pb.v, acc[0], 0, 0, 0, SCL1, 0, SCL1);
        acc[1] = __builtin_amdgcn_mfma_scale_f32_32x32x64_f8f6f4(
            vf1.v, pb.v, acc[1], 0, 0, 0, SCL1, 0, SCL1);
    }

    // ---- write per-wave partial state to LDS ----
    #pragma unroll
    for (int ct = 0; ct < 2; ++ct)
        #pragma unroll
        for (int r = 0; r < 16; ++r) {
            const int c = ct * 32 + (r & 3) + 8 * (r >> 2) + 4 * h2;
            smem[w][i_l * 65 + c] = acc[ct][r];
        }
    if (h2 == 0) lbuf[w][i_l] = l_;
    __syncthreads();

    // ---- combine 8 partials (plain sums) + epilogue ----
    const int q  = tid & 31;
    const int c0 = (tid >> 5) * 4;

    float Ls = 0.f, O[4] = { 0.f, 0.f, 0.f, 0.f };
    #pragma unroll
    for (int s2 = 0; s2 < NW; ++s2) {
        Ls += lbuf[s2][q];
        #pragma unroll
        for (int k = 0; k < 4; ++k)
            O[k] += smem[s2][q * 65 + c0 + k];
    }
    const float rl    = __builtin_amdgcn_rcpf(Ls);
    const float alpha = alphap[0];

    #pragma unroll
    for (int k = 0; k < 4; ++k) {
        const size_t idx = ((size_t)(nb * NCH + c0 + k)) * L_SEQ + i0 + q;
        out[idx] = alpha * O[k] * rl + x[idx];
    }
}

extern "C" void kernel_launch(void* const* d_in, const int* in_sizes, int n_in,
                              void* d_out, int out_size, void* d_ws, size_t ws_size,
                              hipStream_t stream) {
    const float* x     = (const float*)d_in[0];
    const float* wb    = (const float*)d_in[1];
    const float* bb    = (const float*)d_in[2];
    const float* wc    = (const float*)d_in[3];
    const float* bc    = (const float*)d_in[4];
    const float* wd    = (const float*)d_in[5];
    const float* bd    = (const float*)d_in[6];
    const float* alpha = (const float*)d_in[7];

    const size_t elems = (size_t)NBATCH * L_SEQ * NCH;  // 1,048,576 bytes each (fp8)
    u8* Qp8 = (u8*)d_ws;
    u8* Kp8 = Qp8 + elems;
    u8* Vp8 = Kp8 + elems;

    qkv_kernel<<<dim3(L_SEQ / 32, NBATCH), 256, 0, stream>>>(
        x, wb, bb, wc, bc, wd, bd, Qp8, Kp8, Vp8);
    attn_kernel<<<dim3(L_SEQ / QB, NBATCH), 512, 0, stream>>>(
        Qp8, Kp8, Vp8, x, alpha, (float*)d_out);
}

// Round 20
// 39.022 us; speedup vs baseline: 1.0977x; 1.0977x over previous
//
#include <hip/hip_runtime.h>
#include <hip/hip_bf16.h>

typedef unsigned short u16;
typedef unsigned char u8;
typedef unsigned int u32;
typedef __attribute__((ext_vector_type(4))) unsigned int u32x4;
typedef __attribute__((ext_vector_type(8))) int i32x8;
typedef __attribute__((ext_vector_type(16))) float f32x16;

#define L_SEQ 4096
#define NCH 64
#define NBATCH 4
#define NW 8                    // waves per block = KV splits
#define KVSPAN (L_SEQ / NW)     // 512 j per wave (8 tiles of 64)
#define TPS (KVSPAN / 64)
#define QB 32                   // q-rows per block (shared by all waves)
#define LOG2E 1.4426950408889634f
#define C2 (3.0f * LOG2E)       // constant softmax shift; cancels in O/l
#define SCL1 127                // e8m0 encoding of 1.0

// packed f32 pair -> 2x fp8 e4m3 into low (WORD=false) or high (WORD=true) 16 bits.
template <bool WORD>
__device__ inline u32 pk_fp8(float a, float b, u32 old) {
    return (u32)__builtin_amdgcn_cvt_pk_fp8_f32(a, b, (int)old, WORD);
}
__device__ inline u8 fp8_1(float a) {
    return (u8)(__builtin_amdgcn_cvt_pk_fp8_f32(a, a, 0, false) & 0xff);
}

union I8 { u32x4 q[2]; i32x8 v; };
union PU { u32 u[8]; i32x8 v; };

// ---------------- Kernel 1: QKV projection -> fp8 fragment-order workspace --------
// (R17-proven: 32-px blocks, 512 blocks = 2 blocks/CU, 8 waves/CU.)
// Qp8[n][i][c] row-major, Q pre-scaled by log2e.
// Kp8 addr(j,c) = (j>>5)*2048 + ((c>>4)&1)*1024 + ((j&31)+((c>>5)<<5))*16 + (c&15).
// Vp8 addr(c,j) = (j>>6)*4096 + (c>>5)*2048 + ((j>>5)&1)*1024
//               + ((c&31)+(h<<5))*16 + el,  h=((j&31)>>2)&1, el=(j&3)+4*((j&31)>>3).
__global__ __launch_bounds__(256) void qkv_kernel(
    const float* __restrict__ x,
    const float* __restrict__ wb, const float* __restrict__ bb,
    const float* __restrict__ wc, const float* __restrict__ bc,
    const float* __restrict__ wd, const float* __restrict__ bd,
    u8* __restrict__ Qp8, u8* __restrict__ Kp8, u8* __restrict__ Vp8)
{
    __shared__ float xs[64][32];       // x tile: [c][px], 8 KB
    __shared__ float wl[3][64][65];    // padded weights: [mat][o][c], 49.9 KB

    const int nb  = blockIdx.y;
    const int i0  = blockIdx.x * 32;
    const int tid = threadIdx.x;

    const float* xbase = x + (size_t)nb * NCH * L_SEQ + i0;
    #pragma unroll
    for (int rep = 0; rep < 8; ++rep) {
        int idx = rep * 256 + tid;
        int c = idx >> 5, px = idx & 31;
        xs[c][px] = xbase[(size_t)c * L_SEQ + px];
    }
    const float* wsrc[3] = { wb, wc, wd };
    for (int m = 0; m < 3; ++m) {
        #pragma unroll
        for (int rep = 0; rep < 16; ++rep) {
            int idx = rep * 256 + tid;
            wl[m][idx >> 6][idx & 63] = wsrc[m][idx];
        }
    }
    __syncthreads();

    const int co  = tid & 63;     // output channel
    const int pg  = tid >> 6;     // pixel group 0..3 (8 px each)
    const int px0 = pg * 8;

    float accB[8], accC[8], accD[8];
    const float biasB = bb[co], biasC = bc[co], biasD = bd[co];
    #pragma unroll
    for (int p = 0; p < 8; ++p) { accB[p] = biasB; accC[p] = biasC; accD[p] = biasD; }

    for (int c = 0; c < 64; ++c) {
        const float wbv = wl[0][co][c];
        const float wcv = wl[1][co][c];
        const float wdv = wl[2][co][c];
        #pragma unroll
        for (int p = 0; p < 8; ++p) {
            const float xv = xs[c][px0 + p];
            accB[p] += wbv * xv;
            accC[p] += wcv * xv;
            accD[p] += wdv * xv;
        }
    }

    const size_t nbase = (size_t)nb * L_SEQ * NCH;   // bytes per batch = 262144

    const int kbase = (i0 >> 5) * 2048 + ((co >> 4) & 1) * 1024 + (co >> 5) * 512
                    + pg * 128 + (co & 15);
    const int vbase = (i0 >> 6) * 4096 + (co >> 5) * 2048 + ((i0 >> 5) & 1) * 1024
                    + (co & 31) * 16 + 4 * pg;

    #pragma unroll
    for (int p = 0; p < 8; ++p) {
        const int i = i0 + px0 + p;
        Kp8[nbase + kbase + p * 16]      = fp8_1(accB[p]);                   // keys = xb
        Qp8[nbase + (size_t)i * 64 + co] = fp8_1(accC[p] * LOG2E);           // queries (log2e-folded)
    }
    {                                                                         // values = xd
        u32 w0 = pk_fp8<false>(accD[0], accD[1], 0);
        w0     = pk_fp8<true >(accD[2], accD[3], w0);
        u32 w1 = pk_fp8<false>(accD[4], accD[5], 0);
        w1     = pk_fp8<true >(accD[6], accD[7], w1);
        *(u32*)&Vp8[nbase + vbase]       = w0;
        *(u32*)&Vp8[nbase + vbase + 512] = w1;
    }
}

// ---------------- Kernel 2: flash attention, MX-scaled 32x32x64 fp8 ---------------
// (R17 exact — best measured total 38.7us, absmax 0.0156.)
// 8 waves share one 32-row q-tile; wave w owns 512 j. 4x mfma_scale 32x32x64 per
// tile (unit scales). Swapped QK^T; sigma-mapped lane-local P packing; constant-
// shift softmax (no max state); single shfl per row; plain-sum combine.
// (512,4): R18 proved (512,2) is worse (occupancy loss, no spill at 128 VGPR).
__global__ __launch_bounds__(512, 4) void attn_kernel(
    const u8* __restrict__ Qp8, const u8* __restrict__ Kp8,
    const u8* __restrict__ Vp8, const float* __restrict__ x,
    const float* __restrict__ alphap, float* __restrict__ out)
{
    __shared__ float smem[NW][QB * 65];   // per-wave partial O [q][c], pad 65
    __shared__ float lbuf[NW][QB];        // per-wave partial l

    const int nb   = blockIdx.y;
    const int i0   = blockIdx.x * QB;
    const int tid  = threadIdx.x;
    const int w    = tid >> 6;
    const int lane = tid & 63;
    const int i_l  = lane & 31;    // q-row owned by this lane
    const int h2   = lane >> 5;    // k-half

    // Q fragment (B operand): B[k=c=h2*32+e][col=i], 32 consecutive bytes
    I8 qf;
    {
        const u8* qrow = Qp8 + (size_t)(nb * L_SEQ + i0 + i_l) * 64 + h2 * 32;
        qf.q[0] = *(const u32x4*)(qrow);
        qf.q[1] = *(const u32x4*)(qrow + 16);
    }

    f32x16 acc[2] = {};   // [ct]: O^T[c = ct*32 + (r&3)+8*(r>>2)+4*h2][i = i_l]
    float l_ = 0.f;

    const u8* KpB = Kp8 + (size_t)nb * L_SEQ * NCH;
    const u8* VpB = Vp8 + (size_t)nb * NCH * L_SEQ;

    #pragma unroll 1
    for (int t = 0; t < TPS; ++t) {
        const int j0 = w * KVSPAN + t * 64;

        // ---- coalesced fragment loads: 8x dwordx4 per tile ----
        I8 kf0, kf1, vf0, vf1;
        {
            const u8* kb = KpB + (size_t)(j0 >> 5) * 2048 + lane * 16;
            kf0.q[0] = *(const u32x4*)(kb);
            kf0.q[1] = *(const u32x4*)(kb + 1024);
            kf1.q[0] = *(const u32x4*)(kb + 2048);
            kf1.q[1] = *(const u32x4*)(kb + 3072);
            const u8* vb = VpB + (size_t)(j0 >> 6) * 4096 + lane * 16;
            vf0.q[0] = *(const u32x4*)(vb);
            vf0.q[1] = *(const u32x4*)(vb + 1024);
            vf1.q[0] = *(const u32x4*)(vb + 2048);
            vf1.q[1] = *(const u32x4*)(vb + 3072);
        }

        // ---- S^T = K Q^T (two 32j x 32i MFMA over K=64) ----
        f32x16 z = {};
        f32x16 s0 = __builtin_amdgcn_mfma_scale_f32_32x32x64_f8f6f4(
            kf0.v, qf.v, z, 0, 0, 0, SCL1, 0, SCL1);
        f32x16 s1 = __builtin_amdgcn_mfma_scale_f32_32x32x64_f8f6f4(
            kf1.v, qf.v, z, 0, 0, 0, SCL1, 0, SCL1);

        // ---- constant-shift softmax: P' = 2^(S2 - C2) ----
        #pragma unroll
        for (int r = 0; r < 16; ++r) {
            s0[r] = exp2f(s0[r] - C2);
            s1[r] = exp2f(s1[r] - C2);
        }
        {
            const float a0 = (s0[0] + s0[1]) + (s0[2] + s0[3]);
            const float a1 = (s0[4] + s0[5]) + (s0[6] + s0[7]);
            const float a2 = (s0[8] + s0[9]) + (s0[10] + s0[11]);
            const float a3 = (s0[12] + s0[13]) + (s0[14] + s0[15]);
            const float b0 = (s1[0] + s1[1]) + (s1[2] + s1[3]);
            const float b1 = (s1[4] + s1[5]) + (s1[6] + s1[7]);
            const float b2 = (s1[8] + s1[9]) + (s1[10] + s1[11]);
            const float b3 = (s1[12] + s1[13]) + (s1[14] + s1[15]);
            float rs = ((a0 + a1) + (a2 + a3)) + ((b0 + b1) + (b2 + b3));
            rs += __shfl_xor(rs, 32, 64);   // lanes i and i+32 share row i
            l_ += rs;
        }

        // ---- pack P' to fp8 B-fragment: slot e<16 -> s0[e], e>=16 -> s1[e-16] ----
        PU pb;
        #pragma unroll
        for (int r = 0; r < 4; ++r)
            pb.u[r] = pk_fp8<true>(s0[4 * r + 2], s0[4 * r + 3],
                      pk_fp8<false>(s0[4 * r], s0[4 * r + 1], 0));
        #pragma unroll
        for (int r = 0; r < 4; ++r)
            pb.u[4 + r] = pk_fp8<true>(s1[4 * r + 2], s1[4 * r + 3],
                          pk_fp8<false>(s1[4 * r], s1[4 * r + 1], 0));

        // ---- O^T += V^T P'^T (two 32c x 32i MFMA over K=64 j-slots) ----
        acc[0] = __builtin_amdgcn_mfma_scale_f32_32x32x64_f8f6f4(
            vf0.v, pb.v, acc[0], 0, 0, 0, SCL1, 0, SCL1);
        acc[1] = __builtin_amdgcn_mfma_scale_f32_32x32x64_f8f6f4(
            vf1.v, pb.v, acc[1], 0, 0, 0, SCL1, 0, SCL1);
    }

    // ---- write per-wave partial state to LDS ----
    #pragma unroll
    for (int ct = 0; ct < 2; ++ct)
        #pragma unroll
        for (int r = 0; r < 16; ++r) {
            const int c = ct * 32 + (r & 3) + 8 * (r >> 2) + 4 * h2;
            smem[w][i_l * 65 + c] = acc[ct][r];
        }
    if (h2 == 0) lbuf[w][i_l] = l_;
    __syncthreads();

    // ---- combine 8 partials (plain sums) + epilogue ----
    const int q  = tid & 31;
    const int c0 = (tid >> 5) * 4;

    float Ls = 0.f, O[4] = { 0.f, 0.f, 0.f, 0.f };
    #pragma unroll
    for (int s2 = 0; s2 < NW; ++s2) {
        Ls += lbuf[s2][q];
        #pragma unroll
        for (int k = 0; k < 4; ++k)
            O[k] += smem[s2][q * 65 + c0 + k];
    }
    const float rl    = __builtin_amdgcn_rcpf(Ls);
    const float alpha = alphap[0];

    #pragma unroll
    for (int k = 0; k < 4; ++k) {
        const size_t idx = ((size_t)(nb * NCH + c0 + k)) * L_SEQ + i0 + q;
        out[idx] = alpha * O[k] * rl + x[idx];
    }
}

extern "C" void kernel_launch(void* const* d_in, const int* in_sizes, int n_in,
                              void* d_out, int out_size, void* d_ws, size_t ws_size,
                              hipStream_t stream) {
    const float* x     = (const float*)d_in[0];
    const float* wb    = (const float*)d_in[1];
    const float* bb    = (const float*)d_in[2];
    const float* wc    = (const float*)d_in[3];
    const float* bc    = (const float*)d_in[4];
    const float* wd    = (const float*)d_in[5];
    const float* bd    = (const float*)d_in[6];
    const float* alpha = (const float*)d_in[7];

    const size_t elems = (size_t)NBATCH * L_SEQ * NCH;  // 1,048,576 bytes each (fp8)
    u8* Qp8 = (u8*)d_ws;
    u8* Kp8 = Qp8 + elems;
    u8* Vp8 = Kp8 + elems;

    qkv_kernel<<<dim3(L_SEQ / 32, NBATCH), 256, 0, stream>>>(
        x, wb, bb, wc, bc, wd, bd, Qp8, Kp8, Vp8);
    attn_kernel<<<dim3(L_SEQ / QB, NBATCH), 512, 0, stream>>>(
        Qp8, Kp8, Vp8, x, alpha, (float*)d_out);
}